// Round 1
// baseline (437.742 us; speedup 1.0000x reference)
//
#include <hip/hip_runtime.h>
#include <hip/hip_bf16.h>
#include <stdint.h>

typedef unsigned short u16;
typedef __attribute__((ext_vector_type(8))) __bf16 bf16x8;
typedef __attribute__((ext_vector_type(8))) short short8;
typedef __attribute__((ext_vector_type(8))) u16 ushort8;
typedef __attribute__((ext_vector_type(4))) float f32x4;

#define M_TOT 8192
#define N_TOT 8192
#define K_TOT 2048
#define W_COUNT (N_TOT * K_TOT)   // 16,777,216
#define X_COUNT (M_TOT * K_TOT)   // 16,777,216

// ---------------- 1. deterministic two-stage |w| reduction (double) ----------------
__global__ void tl_reduce_abs(const float* __restrict__ w, double* __restrict__ partials) {
    const int tid = blockIdx.x * 256 + threadIdx.x;
    const float4* w4 = (const float4*)w;
    const int n4 = W_COUNT / 4;
    double s = 0.0;
    for (int i = tid; i < n4; i += 1024 * 256) {
        float4 v = w4[i];
        s += (double)fabsf(v.x) + (double)fabsf(v.y) + (double)fabsf(v.z) + (double)fabsf(v.w);
    }
    #pragma unroll
    for (int off = 32; off > 0; off >>= 1) s += __shfl_down(s, off);
    __shared__ double red[4];
    if ((threadIdx.x & 63) == 0) red[threadIdx.x >> 6] = s;
    __syncthreads();
    if (threadIdx.x == 0) partials[blockIdx.x] = (red[0] + red[1]) + (red[2] + red[3]);
}

__global__ void tl_finalize_delta(const double* __restrict__ partials, double* __restrict__ delta) {
    const int t = threadIdx.x; // 256 threads, 1024 partials
    double s = (partials[t] + partials[t + 256]) + (partials[t + 512] + partials[t + 768]);
    #pragma unroll
    for (int off = 32; off > 0; off >>= 1) s += __shfl_down(s, off);
    __shared__ double red[4];
    if ((t & 63) == 0) red[t >> 6] = s;
    __syncthreads();
    if (t == 0) *delta = 0.7 * (((red[0] + red[1]) + (red[2] + red[3])) / (double)W_COUNT);
}

// ---------------- 2. ternarize w -> bf16 {-1,0,+1} ----------------
__global__ void tl_ternarize(const float* __restrict__ w, const double* __restrict__ delta_p,
                             u16* __restrict__ wb) {
    const double d = *delta_p;
    const int i = (blockIdx.x * 256 + threadIdx.x) * 8;
    const float4 v0 = *(const float4*)(w + i);
    const float4 v1 = *(const float4*)(w + i + 4);
    float vv[8] = {v0.x, v0.y, v0.z, v0.w, v1.x, v1.y, v1.z, v1.w};
    ushort8 o;
    #pragma unroll
    for (int j = 0; j < 8; ++j) {
        double wd = (double)vv[j];
        u16 q = 0;
        if (wd > d)       q = 0x3F80;  // +1.0 bf16
        else if (wd < -d) q = 0xBF80;  // -1.0 bf16
        o[j] = q;
    }
    *(ushort8*)(wb + i) = o;
}

// ---------------- 3. x -> bf16 (RNE) ----------------
__global__ void tl_cvt_x(const float* __restrict__ x, u16* __restrict__ xb) {
    const int i = (blockIdx.x * 256 + threadIdx.x) * 8;
    const float4 v0 = *(const float4*)(x + i);
    const float4 v1 = *(const float4*)(x + i + 4);
    float vv[8] = {v0.x, v0.y, v0.z, v0.w, v1.x, v1.y, v1.z, v1.w};
    ushort8 o;
    #pragma unroll
    for (int j = 0; j < 8; ++j) {
        uint32_t u = __float_as_uint(vv[j]);
        uint32_t r = (u + 0x7FFFu + ((u >> 16) & 1u)) >> 16;  // round-to-nearest-even
        o[j] = (u16)r;
    }
    *(ushort8*)(xb + i) = o;
}

// ---------------- 4. bf16 MFMA GEMM, B^T layout (m97 structure) ----------------
// C[m][n] = alpha * sum_k A[m][k]*B[n][k] + bias[n]
// 128x128 tile, BK=64, 4 waves (2x2), each wave 64x64 via 4x4 of 16x16x32 MFMA.
__global__ __launch_bounds__(256) void tl_gemm(
    const u16* __restrict__ A, const u16* __restrict__ Bm,
    const float* __restrict__ alpha_p, const float* __restrict__ bias,
    float* __restrict__ C) {
    __shared__ alignas(16) u16 As[128 * 64];
    __shared__ alignas(16) u16 Bs[128 * 64];

    const int t = threadIdx.x;
    const int w = t >> 6;
    const int l = t & 63;

    // XCD-aware swizzle (nwg=4096, divisible by 8)
    const int bid = blockIdx.x;
    const int swz = (bid & 7) * (4096 >> 3) + (bid >> 3);
    const int tm = swz >> 6;   // 64 N-tiles per M-row
    const int tn = swz & 63;

    const int rowA0 = tm * 128;
    const int rowB0 = tn * 128;

    // staging coords: thread t covers 16B at LDS flat offset i*4096 + t*16
    const int srow = t >> 3;          // 0..31 (row within 32-row group)
    const int skel = (t & 7) * 8;     // k-element offset (8 bf16 = 16B)

    const u16* aPtr = A + (size_t)(rowA0 + srow) * K_TOT + skel;
    const u16* bPtr = Bm + (size_t)(rowB0 + srow) * K_TOT + skel;

    f32x4 acc[4][4] = {};

    const int wr = (w >> 1) * 64;
    const int wc = (w & 1) * 64;
    const int r16 = l & 15;
    const int kq = l >> 4;

    for (int k0 = 0; k0 < K_TOT; k0 += 64) {
        #pragma unroll
        for (int i = 0; i < 4; ++i) {
            __builtin_amdgcn_global_load_lds(
                (const __attribute__((address_space(1))) void*)(aPtr + (size_t)(i * 32) * K_TOT + k0),
                (__attribute__((address_space(3))) void*)&As[i * 2048 + w * 512], 16, 0, 0);
        }
        #pragma unroll
        for (int i = 0; i < 4; ++i) {
            __builtin_amdgcn_global_load_lds(
                (const __attribute__((address_space(1))) void*)(bPtr + (size_t)(i * 32) * K_TOT + k0),
                (__attribute__((address_space(3))) void*)&Bs[i * 2048 + w * 512], 16, 0, 0);
        }
        __syncthreads();   // drains vmcnt before use (m97 structure)

        #pragma unroll
        for (int kk = 0; kk < 2; ++kk) {
            short8 af[4], bf[4];
            #pragma unroll
            for (int mi = 0; mi < 4; ++mi)
                af[mi] = *(const short8*)&As[(wr + mi * 16 + r16) * 64 + kk * 32 + kq * 8];
            #pragma unroll
            for (int ni = 0; ni < 4; ++ni)
                bf[ni] = *(const short8*)&Bs[(wc + ni * 16 + r16) * 64 + kk * 32 + kq * 8];
            #pragma unroll
            for (int mi = 0; mi < 4; ++mi) {
                #pragma unroll
                for (int ni = 0; ni < 4; ++ni) {
                    acc[mi][ni] = __builtin_amdgcn_mfma_f32_16x16x32_bf16(
                        __builtin_bit_cast(bf16x8, af[mi]),
                        __builtin_bit_cast(bf16x8, bf[ni]),
                        acc[mi][ni], 0, 0, 0);
                }
            }
        }
        __syncthreads();
    }

    const float alpha = *alpha_p;
    const int crow0 = rowA0 + wr + kq * 4;   // D layout: row = (l>>4)*4 + reg
    const int ccol0 = rowB0 + wc + r16;      //           col = l&15
    #pragma unroll
    for (int ni = 0; ni < 4; ++ni) {
        const int col = ccol0 + ni * 16;
        const float bv = bias[col];
        #pragma unroll
        for (int mi = 0; mi < 4; ++mi) {
            #pragma unroll
            for (int r = 0; r < 4; ++r) {
                C[(size_t)(crow0 + mi * 16 + r) * N_TOT + col] = acc[mi][ni][r] * alpha + bv;
            }
        }
    }
}

extern "C" void kernel_launch(void* const* d_in, const int* in_sizes, int n_in,
                              void* d_out, int out_size, void* d_ws, size_t ws_size,
                              hipStream_t stream) {
    const float* x     = (const float*)d_in[0];
    const float* wgt   = (const float*)d_in[1];
    const float* alpha = (const float*)d_in[2];
    const float* bias  = (const float*)d_in[3];
    float* out = (float*)d_out;

    char* ws = (char*)d_ws;
    double* partials = (double*)ws;                         // 1024 * 8B = 8 KB
    double* delta    = (double*)(ws + 8192);                // 8 B
    u16* xb = (u16*)(ws + 16384);                           // 32 MB
    u16* wb = (u16*)(ws + 16384 + (size_t)X_COUNT * 2);     // 32 MB

    tl_reduce_abs<<<1024, 256, 0, stream>>>(wgt, partials);
    tl_finalize_delta<<<1, 256, 0, stream>>>(partials, delta);
    tl_ternarize<<<W_COUNT / (256 * 8), 256, 0, stream>>>(wgt, delta, wb);
    tl_cvt_x<<<X_COUNT / (256 * 8), 256, 0, stream>>>(x, xb);
    tl_gemm<<<(M_TOT / 128) * (N_TOT / 128), 256, 0, stream>>>(xb, wb, alpha, bias, out);
}

// Round 2
// 328.981 us; speedup vs baseline: 1.3306x; 1.3306x over previous
//
#include <hip/hip_runtime.h>
#include <hip/hip_bf16.h>
#include <stdint.h>

typedef unsigned short u16;
typedef __attribute__((ext_vector_type(8))) __bf16 bf16x8;
typedef __attribute__((ext_vector_type(8))) short short8;
typedef __attribute__((ext_vector_type(8))) u16 ushort8;
typedef __attribute__((ext_vector_type(4))) float f32x4;

#define M_TOT 8192
#define N_TOT 8192
#define K_TOT 2048
#define W_COUNT (N_TOT * K_TOT)
#define X_COUNT (M_TOT * K_TOT)

// ---------------- 1. deterministic two-stage |w| reduction (double) ----------------
__global__ void tl_reduce_abs(const float* __restrict__ w, double* __restrict__ partials) {
    const int tid = blockIdx.x * 256 + threadIdx.x;
    const float4* w4 = (const float4*)w;
    const int n4 = W_COUNT / 4;
    double s = 0.0;
    for (int i = tid; i < n4; i += 1024 * 256) {
        float4 v = w4[i];
        s += (double)fabsf(v.x) + (double)fabsf(v.y) + (double)fabsf(v.z) + (double)fabsf(v.w);
    }
    #pragma unroll
    for (int off = 32; off > 0; off >>= 1) s += __shfl_down(s, off);
    __shared__ double red[4];
    if ((threadIdx.x & 63) == 0) red[threadIdx.x >> 6] = s;
    __syncthreads();
    if (threadIdx.x == 0) partials[blockIdx.x] = (red[0] + red[1]) + (red[2] + red[3]);
}

__global__ void tl_finalize_delta(const double* __restrict__ partials, double* __restrict__ delta) {
    const int t = threadIdx.x;
    double s = (partials[t] + partials[t + 256]) + (partials[t + 512] + partials[t + 768]);
    #pragma unroll
    for (int off = 32; off > 0; off >>= 1) s += __shfl_down(s, off);
    __shared__ double red[4];
    if ((t & 63) == 0) red[t >> 6] = s;
    __syncthreads();
    if (t == 0) *delta = 0.7 * (((red[0] + red[1]) + (red[2] + red[3])) / (double)W_COUNT);
}

// ---------------- 2. ternarize w -> bf16 {-1,0,+1} ----------------
__global__ void tl_ternarize(const float* __restrict__ w, const double* __restrict__ delta_p,
                             u16* __restrict__ wb) {
    const double d = *delta_p;
    const int i = (blockIdx.x * 256 + threadIdx.x) * 8;
    const float4 v0 = *(const float4*)(w + i);
    const float4 v1 = *(const float4*)(w + i + 4);
    float vv[8] = {v0.x, v0.y, v0.z, v0.w, v1.x, v1.y, v1.z, v1.w};
    ushort8 o;
    #pragma unroll
    for (int j = 0; j < 8; ++j) {
        double wd = (double)vv[j];
        u16 q = 0;
        if (wd > d)       q = 0x3F80;
        else if (wd < -d) q = 0xBF80;
        o[j] = q;
    }
    *(ushort8*)(wb + i) = o;
}

// ---------------- 3. x -> bf16 (RNE) ----------------
__global__ void tl_cvt_x(const float* __restrict__ x, u16* __restrict__ xb) {
    const int i = (blockIdx.x * 256 + threadIdx.x) * 8;
    const float4 v0 = *(const float4*)(x + i);
    const float4 v1 = *(const float4*)(x + i + 4);
    float vv[8] = {v0.x, v0.y, v0.z, v0.w, v1.x, v1.y, v1.z, v1.w};
    ushort8 o;
    #pragma unroll
    for (int j = 0; j < 8; ++j) {
        uint32_t u = __float_as_uint(vv[j]);
        uint32_t r = (u + 0x7FFFu + ((u >> 16) & 1u)) >> 16;
        o[j] = (u16)r;
    }
    *(ushort8*)(xb + i) = o;
}

// ---------------- 4. 256x256 deep-pipelined bf16 MFMA GEMM (8-phase-style) ----------
// C[m][n] = alpha * sum_k A[m][k]*B[n][k] + bias[n]   (both A,B row-major over K)
// 512 threads = 8 waves (2 Mrows x 4 Ncols), each wave owns 128x64 of C.
// LDS: per operand 4 slots of 16KB: slot(p = kt&1, h = k-half). 128 KiB total.
// Slot layout: [256 rows][32 kelems] bf16, XOR-swizzled: byte ^= ((byte>>7)&3)<<4.
// Per phase: {ds_reads | 1 half-tile stage (2x global_load_lds w16)} ; s_barrier;
// lgkmcnt(0); setprio(1); 16 MFMA; setprio(0); [vmcnt(4) gate]; s_barrier.

#define SB    __builtin_amdgcn_sched_barrier(0)
#define BARR  __builtin_amdgcn_s_barrier()
#define LGKM0 asm volatile("s_waitcnt lgkmcnt(0)" ::: "memory")
#define VMW(N) asm volatile("s_waitcnt vmcnt(" #N ")" ::: "memory")

#define STAGE(XSRC, XBASE, P, H, KT) do {                                              \
    const u16* s_ = (XSRC) + (size_t)(KT) * 64 + (H) * 32;                             \
    const int db_ = (XBASE) + (((P) * 2 + (H)) * 16384) + wid * 1024;                  \
    __builtin_amdgcn_global_load_lds(                                                  \
        (const __attribute__((address_space(1))) void*)s_,                             \
        (__attribute__((address_space(3))) void*)((char*)lds + db_), 16, 0, 0);        \
    __builtin_amdgcn_global_load_lds(                                                  \
        (const __attribute__((address_space(1))) void*)(s_ + (size_t)128 * K_TOT),     \
        (__attribute__((address_space(3))) void*)((char*)lds + db_ + 8192), 16, 0, 0); \
} while (0)

#define READ_A(P, KK, G) do {                                                          \
    const int ab_ = ((P) * 2 + (KK)) * 16384 + wr * 8192 + laneRd;                     \
    _Pragma("unroll") for (int mi_ = 0; mi_ < 4; ++mi_)                                \
        aF[mi_] = *(const short8*)((const char*)lds + ab_ + ((G) * 4 + mi_) * 1024);   \
} while (0)

#define READ_B(P, KK) do {                                                             \
    const int bb_ = 65536 + ((P) * 2 + (KK)) * 16384 + wc * 4096 + laneRd;             \
    _Pragma("unroll") for (int ni_ = 0; ni_ < 4; ++ni_)                                \
        bF[ni_] = *(const short8*)((const char*)lds + bb_ + ni_ * 1024);               \
} while (0)

#define MFMA16(G) do {                                                                 \
    _Pragma("unroll") for (int mi_ = 0; mi_ < 4; ++mi_)                                \
    _Pragma("unroll") for (int ni_ = 0; ni_ < 4; ++ni_)                                \
        acc[(G) * 4 + mi_][ni_] = __builtin_amdgcn_mfma_f32_16x16x32_bf16(             \
            __builtin_bit_cast(bf16x8, aF[mi_]), __builtin_bit_cast(bf16x8, bF[ni_]),  \
            acc[(G) * 4 + mi_][ni_], 0, 0, 0);                                         \
} while (0)

#define PHASE_CORE(G) \
    SB; BARR; LGKM0; SB;                                                               \
    __builtin_amdgcn_s_setprio(1); MFMA16(G); __builtin_amdgcn_s_setprio(0); SB;

#define DO_KTILE(P, KT, STG, G2GATE)                                                   \
    /* ph1: kk0, fm 0-3 */                                                             \
    READ_A(P, 0, 0); READ_B(P, 0);                                                     \
    if (STG) STAGE(aSrc, 0, (P) ^ 1, 0, (KT) + 1);                                     \
    PHASE_CORE(0); BARR;                                                               \
    /* ph2: kk0, fm 4-7 */                                                             \
    READ_A(P, 0, 1);                                                                   \
    if (STG) STAGE(bSrc, 65536, (P) ^ 1, 0, (KT) + 1);                                 \
    PHASE_CORE(1); G2GATE; BARR;                                                       \
    /* ph3: kk1, fm 0-3 */                                                             \
    READ_A(P, 1, 0); READ_B(P, 1);                                                     \
    if (STG) STAGE(aSrc, 0, (P) ^ 1, 1, (KT) + 1);                                     \
    PHASE_CORE(0); BARR;                                                               \
    /* ph4: kk1, fm 4-7 */                                                             \
    READ_A(P, 1, 1);                                                                   \
    if (STG) STAGE(bSrc, 65536, (P) ^ 1, 1, (KT) + 1);                                 \
    PHASE_CORE(1); VMW(4); BARR;

__global__ __launch_bounds__(512, 2) void tl_gemm256(
    const u16* __restrict__ A, const u16* __restrict__ Bm,
    const float* __restrict__ alpha_p, const float* __restrict__ bias,
    float* __restrict__ C) {
    __shared__ __attribute__((aligned(128))) u16 lds[65536];  // 128 KiB

    const int t = threadIdx.x;
    const int wid = t >> 6;
    const int l = t & 63;
    const int wr = wid >> 2;   // 0..1
    const int wc = wid & 3;    // 0..3

    const int bid = blockIdx.x;
    const int swz = (bid & 7) * 128 + (bid >> 3);   // nwg=1024, bijective
    const int tm = swz >> 5, tn = swz & 31;
    const int row0 = tm * 256, col0 = tn * 256;

    // staging: per-thread source coords (inverse-swizzled global source, linear LDS dest)
    const int d0 = t * 16;
    const int os0 = d0 ^ (((d0 >> 7) & 3) << 4);
    const int sr0 = os0 >> 6;          // 0..127
    const int sc0 = (os0 & 63) >> 1;   // 0..31, multiple of 8
    const u16* aSrc = A + (size_t)(row0 + sr0) * K_TOT + sc0;
    const u16* bSrc = Bm + (size_t)(col0 + sr0) * K_TOT + sc0;

    // ds_read lane constants: row=rlane (+16*fm +128*wr), kq = quad of 8 k-elems
    const int rlane = l & 15, kq = l >> 4;
    const int laneRd = rlane * 64 + ((kq * 16) ^ (((rlane >> 1) & 3) << 4));

    f32x4 acc[8][4] = {};
    short8 aF[4], bF[4];

    // prologue: stage kt0 (parity 0): Ah0, Bh0, Ah1, Bh1
    STAGE(aSrc, 0, 0, 0, 0);
    STAGE(bSrc, 65536, 0, 0, 0);
    STAGE(aSrc, 0, 0, 1, 0);
    STAGE(bSrc, 65536, 0, 1, 0);
    VMW(4); BARR;

    #pragma unroll 1
    for (int i = 0; i < 15; ++i) {
        const int k0 = 2 * i;
        DO_KTILE(0, k0, 1, VMW(4));
        DO_KTILE(1, k0 + 1, 1, VMW(4));
    }
    DO_KTILE(0, 30, 1, VMW(4));
    DO_KTILE(1, 31, 0, VMW(0));

    // epilogue: C = alpha*acc + bias
    const float alpha = *alpha_p;
    const int crow = row0 + wr * 128 + kq * 4;
    const int ccol = col0 + wc * 64 + rlane;
    #pragma unroll
    for (int fn = 0; fn < 4; ++fn) {
        const float bv = bias[ccol + fn * 16];
        #pragma unroll
        for (int fm = 0; fm < 8; ++fm) {
            #pragma unroll
            for (int r = 0; r < 4; ++r) {
                C[(size_t)(crow + fm * 16 + r) * N_TOT + (ccol + fn * 16)] =
                    acc[fm][fn][r] * alpha + bv;
            }
        }
    }
}

extern "C" void kernel_launch(void* const* d_in, const int* in_sizes, int n_in,
                              void* d_out, int out_size, void* d_ws, size_t ws_size,
                              hipStream_t stream) {
    const float* x     = (const float*)d_in[0];
    const float* wgt   = (const float*)d_in[1];
    const float* alpha = (const float*)d_in[2];
    const float* bias  = (const float*)d_in[3];
    float* out = (float*)d_out;

    char* ws = (char*)d_ws;
    double* partials = (double*)ws;
    double* delta    = (double*)(ws + 8192);
    u16* xb = (u16*)(ws + 16384);
    u16* wb = (u16*)(ws + 16384 + (size_t)X_COUNT * 2);

    tl_reduce_abs<<<1024, 256, 0, stream>>>(wgt, partials);
    tl_finalize_delta<<<1, 256, 0, stream>>>(partials, delta);
    tl_ternarize<<<W_COUNT / (256 * 8), 256, 0, stream>>>(wgt, delta, wb);
    tl_cvt_x<<<X_COUNT / (256 * 8), 256, 0, stream>>>(x, xb);
    tl_gemm256<<<(M_TOT / 256) * (N_TOT / 256), 512, 0, stream>>>(xb, wb, alpha, bias, out);
}

// Round 3
// 230.459 us; speedup vs baseline: 1.8994x; 1.4275x over previous
//
#include <hip/hip_runtime.h>
#include <hip/hip_bf16.h>
#include <stdint.h>

typedef __attribute__((ext_vector_type(4))) int i32x4;
typedef signed char s8;

#define M_TOT 8192
#define N_TOT 8192
#define K_TOT 2048
#define W_COUNT (N_TOT * K_TOT)
#define X_COUNT (M_TOT * K_TOT)

// ---------------- 1. fused deterministic reductions: sum|w| (double), max|x| ----------
__global__ void tl_reduce(const float* __restrict__ w, const float* __restrict__ x,
                          double* __restrict__ wsum, float* __restrict__ xmax) {
    const int b = blockIdx.x;
    if (b < 1024) {
        const int tid = b * 256 + threadIdx.x;
        const float4* w4 = (const float4*)w;
        double s = 0.0;
        for (int i = tid; i < W_COUNT / 4; i += 1024 * 256) {
            float4 v = w4[i];
            s += (double)fabsf(v.x) + (double)fabsf(v.y) + (double)fabsf(v.z) + (double)fabsf(v.w);
        }
        #pragma unroll
        for (int off = 32; off > 0; off >>= 1) s += __shfl_down(s, off);
        __shared__ double red[4];
        if ((threadIdx.x & 63) == 0) red[threadIdx.x >> 6] = s;
        __syncthreads();
        if (threadIdx.x == 0) wsum[b] = (red[0] + red[1]) + (red[2] + red[3]);
    } else {
        const int tid = (b - 1024) * 256 + threadIdx.x;
        const float4* x4 = (const float4*)x;
        float m = 0.0f;
        for (int i = tid; i < X_COUNT / 4; i += 1024 * 256) {
            float4 v = x4[i];
            m = fmaxf(m, fmaxf(fmaxf(fabsf(v.x), fabsf(v.y)), fmaxf(fabsf(v.z), fabsf(v.w))));
        }
        #pragma unroll
        for (int off = 32; off > 0; off >>= 1) m = fmaxf(m, __shfl_down(m, off));
        __shared__ float redm[4];
        if ((threadIdx.x & 63) == 0) redm[threadIdx.x >> 6] = m;
        __syncthreads();
        if (threadIdx.x == 0) xmax[b - 1024] = fmaxf(fmaxf(redm[0], redm[1]), fmaxf(redm[2], redm[3]));
    }
}

__global__ void tl_finalize(const double* __restrict__ wsum, const float* __restrict__ xmax,
                            const float* __restrict__ alpha,
                            double* __restrict__ delta, float* __restrict__ qp) {
    const int t = threadIdx.x;
    double s = (wsum[t] + wsum[t + 256]) + (wsum[t + 512] + wsum[t + 768]);
    float m = fmaxf(fmaxf(xmax[t], xmax[t + 256]), fmaxf(xmax[t + 512], xmax[t + 768]));
    #pragma unroll
    for (int off = 32; off > 0; off >>= 1) {
        s += __shfl_down(s, off);
        m = fmaxf(m, __shfl_down(m, off));
    }
    __shared__ double rs[4];
    __shared__ float rm[4];
    if ((t & 63) == 0) { rs[t >> 6] = s; rm[t >> 6] = m; }
    __syncthreads();
    if (t == 0) {
        *delta = 0.7 * (((rs[0] + rs[1]) + (rs[2] + rs[3])) / (double)W_COUNT);
        float mm = fmaxf(fmaxf(rm[0], rm[1]), fmaxf(rm[2], rm[3]));
        qp[0] = 127.0f / mm;                   // x quant scale
        qp[1] = alpha[0] * (mm / 127.0f);      // output scale
    }
}

// ---------------- 2. ternarize w -> i8 {-1,0,+1} ----------------
__global__ void tl_tern_w(const float* __restrict__ w, const double* __restrict__ delta_p,
                          s8* __restrict__ wb) {
    const double d = *delta_p;
    const int i = (blockIdx.x * 256 + threadIdx.x) * 16;
    union { s8 c[16]; i32x4 v; } o;
    #pragma unroll
    for (int j = 0; j < 16; j += 4) {
        float4 v = *(const float4*)(w + i + j);
        float f[4] = {v.x, v.y, v.z, v.w};
        #pragma unroll
        for (int r = 0; r < 4; ++r) {
            double wd = (double)f[r];
            o.c[j + r] = wd > d ? 1 : (wd < -d ? -1 : 0);
        }
    }
    *(i32x4*)(wb + i) = o.v;
}

// ---------------- 3. quantize x -> i8 (RNE, clamp 127) ----------------
__global__ void tl_quant_x(const float* __restrict__ x, const float* __restrict__ qp,
                           s8* __restrict__ xb) {
    const float inv = qp[0];
    const int i = (blockIdx.x * 256 + threadIdx.x) * 16;
    union { s8 c[16]; i32x4 v; } o;
    #pragma unroll
    for (int j = 0; j < 16; j += 4) {
        float4 v = *(const float4*)(x + i + j);
        float f[4] = {v.x, v.y, v.z, v.w};
        #pragma unroll
        for (int r = 0; r < 4; ++r) {
            int q = (int)__builtin_rintf(f[r] * inv);
            q = q > 127 ? 127 : (q < -127 ? -127 : q);
            o.c[j + r] = (s8)q;
        }
    }
    *(i32x4*)(xb + i) = o.v;
}

// ---------------- 4. i8 MFMA GEMM, 256x256 tile, BK=64, 3-slot LDS rotation --------
// C[m][n] = out_scale * (sum_k xq[m][k]*wt[n][k]) + bias[n]
// 512 threads = 8 waves (2 Mrows x 4 Ncols); wave owns 128x64 of C.
// LDS: A slots s*16384, B slots 49152+s*16384, s=0..2 (96 KiB).
// Slot layout [256 rows][64 k] i8, swizzle S(L) = L ^ (((L>>6)&3)<<4) (involution).
// Per K-tile: 2 phases x 16 MFMA (i32_16x16x64_i8); stage t+2 (4 x 16B-loads/thread
// spread over phases); gate vmcnt(4) once per tile (2-K-tile prefetch distance).

#define SB    __builtin_amdgcn_sched_barrier(0)
#define BARR  __builtin_amdgcn_s_barrier()
#define LGKM0 asm volatile("s_waitcnt lgkmcnt(0)" ::: "memory")
#define VMW(N) asm volatile("s_waitcnt vmcnt(" #N ")" ::: "memory")

#define GLDS(SRC, DOFF) __builtin_amdgcn_global_load_lds(                      \
    (const __attribute__((address_space(1))) void*)(SRC),                      \
    (__attribute__((address_space(3))) void*)(lds + (DOFF)), 16, 0, 0)

#define RD_A(S, G) do {                                                        \
    _Pragma("unroll") for (int m_ = 0; m_ < 4; ++m_)                           \
        aF[m_] = *(const i32x4*)(lds + (S) * 16384 + wrOff + ((G) * 4 + m_) * 1024 + lrd); \
} while (0)

#define RD_B(S) do {                                                           \
    _Pragma("unroll") for (int n_ = 0; n_ < 4; ++n_)                           \
        bF[n_] = *(const i32x4*)(lds + 49152 + (S) * 16384 + wcOff + n_ * 1024 + lrd); \
} while (0)

#define MM(G) do {                                                             \
    _Pragma("unroll") for (int m_ = 0; m_ < 4; ++m_)                           \
    _Pragma("unroll") for (int n_ = 0; n_ < 4; ++n_)                           \
        acc[(G) * 4 + m_][n_] = __builtin_amdgcn_mfma_i32_16x16x64_i8(         \
            aF[m_], bF[n_], acc[(G) * 4 + m_][n_], 0, 0, 0);                   \
} while (0)

#define KTILE(S, SSTG, KOFF, DOSTG, GATE) do {                                 \
    RD_A(S, 0); RD_B(S);                                                       \
    if (DOSTG) { GLDS(aSrc + (KOFF), (SSTG) * 16384 + L);                      \
                 GLDS(bSrc + (KOFF), 49152 + (SSTG) * 16384 + L); }            \
    SB; BARR; LGKM0; SB;                                                       \
    __builtin_amdgcn_s_setprio(1); MM(0); __builtin_amdgcn_s_setprio(0); SB; BARR; \
    RD_A(S, 1);                                                                \
    if (DOSTG) { GLDS(aSrc + (KOFF) + 262144, (SSTG) * 16384 + 8192 + L);      \
                 GLDS(bSrc + (KOFF) + 262144, 49152 + (SSTG) * 16384 + 8192 + L); } \
    SB; BARR; LGKM0; SB;                                                       \
    __builtin_amdgcn_s_setprio(1); MM(1); __builtin_amdgcn_s_setprio(0); SB;   \
    GATE; BARR;                                                                \
} while (0)

__global__ __launch_bounds__(512, 2) void tl_gemm_i8(
    const s8* __restrict__ A, const s8* __restrict__ Bm,
    const float* __restrict__ qp, const float* __restrict__ bias,
    float* __restrict__ C) {
    __shared__ __attribute__((aligned(128))) char lds[98304];  // 96 KiB

    const int t = threadIdx.x;
    const int wid = t >> 6;
    const int l = t & 63;
    const int wr = wid >> 2;   // 0..1
    const int wc = wid & 3;    // 0..3

    // rect XCD ordering: resident 32 blocks/XCD = 4tm x 8tn rectangle
    const int bid = blockIdx.x;
    const int x = bid & 7;
    const int j = bid >> 3;                       // 0..127
    const int tm = x * 4 + ((j >> 3) & 3);
    const int tn = (j >> 5) * 8 + (j & 7);
    const int row0 = tm * 256, col0 = tn * 256;

    // staging coords: linear LDS dest L holds logical element S(L) (involution)
    const int L = t * 16;
    const int off = L ^ (((L >> 6) & 3) << 4);
    const int sr = off >> 6;          // 0..127 (row within half)
    const int kb = off & 63;          // 16-aligned k-byte
    const s8* aSrc = A + (size_t)(row0 + sr) * K_TOT + kb;
    const s8* bSrc = Bm + (size_t)(col0 + sr) * K_TOT + kb;

    // ds_read lane constants
    const int rlane = l & 15, kq = l >> 4;
    const int lrd = rlane * 64 + ((kq ^ (rlane & 3)) << 4);
    const int wrOff = wr * 8192;
    const int wcOff = wc * 4096;

    i32x4 acc[8][4] = {};
    i32x4 aF[4], bF[4];

    // prologue: stage tiles 0 (slot0) and 1 (slot1)
    GLDS(aSrc, L);                    GLDS(bSrc, 49152 + L);
    GLDS(aSrc + 262144, 8192 + L);    GLDS(bSrc + 262144, 49152 + 8192 + L);
    GLDS(aSrc + 64, 16384 + L);       GLDS(bSrc + 64, 49152 + 16384 + L);
    GLDS(aSrc + 64 + 262144, 16384 + 8192 + L);
    GLDS(bSrc + 64 + 262144, 49152 + 16384 + 8192 + L);
    VMW(4); BARR;

    int koff = 128;   // staging byte offset for tile t+2
    #pragma unroll 1
    for (int i = 0; i < 10; ++i) {
        KTILE(0, 2, koff, 1, VMW(4)); koff += 64;
        KTILE(1, 0, koff, 1, VMW(4)); koff += 64;
        KTILE(2, 1, koff, 1, VMW(4)); koff += 64;
    }
    KTILE(0, 0, 0, 0, VMW(0));   // tile 30
    KTILE(1, 0, 0, 0, (void)0);  // tile 31

    // epilogue: C = out_scale * acc + bias
    const float osc = qp[1];
    const int crow = row0 + wr * 128 + kq * 4;
    const int ccol = col0 + wc * 64 + rlane;
    #pragma unroll
    for (int fn = 0; fn < 4; ++fn) {
        const float bv = bias[ccol + fn * 16];
        #pragma unroll
        for (int fm = 0; fm < 8; ++fm) {
            #pragma unroll
            for (int r = 0; r < 4; ++r) {
                C[(size_t)(crow + fm * 16 + r) * N_TOT + (ccol + fn * 16)] =
                    (float)acc[fm][fn][r] * osc + bv;
            }
        }
    }
}

extern "C" void kernel_launch(void* const* d_in, const int* in_sizes, int n_in,
                              void* d_out, int out_size, void* d_ws, size_t ws_size,
                              hipStream_t stream) {
    const float* x     = (const float*)d_in[0];
    const float* wgt   = (const float*)d_in[1];
    const float* alpha = (const float*)d_in[2];
    const float* bias  = (const float*)d_in[3];
    float* out = (float*)d_out;

    char* ws = (char*)d_ws;
    double* wsum = (double*)ws;               // 8 KB
    float* xmax  = (float*)(ws + 8192);       // 4 KB
    double* delta = (double*)(ws + 12288);
    float* qp     = (float*)(ws + 12304);     // [0]=127/max, [1]=alpha*max/127
    s8* xb = (s8*)(ws + 16384);               // 16 MB
    s8* wb = (s8*)(ws + 16384 + (size_t)X_COUNT);  // 16 MB

    tl_reduce<<<2048, 256, 0, stream>>>(wgt, x, wsum, xmax);
    tl_finalize<<<1, 256, 0, stream>>>(wsum, xmax, alpha, delta, qp);
    tl_tern_w<<<W_COUNT / (256 * 16), 256, 0, stream>>>(wgt, delta, wb);
    tl_quant_x<<<X_COUNT / (256 * 16), 256, 0, stream>>>(x, qp, xb);
    tl_gemm_i8<<<(M_TOT / 256) * (N_TOT / 256), 512, 0, stream>>>(xb, wb, qp, bias, out);
}

// Round 4
// 212.279 us; speedup vs baseline: 2.0621x; 1.0856x over previous
//
#include <hip/hip_runtime.h>
#include <hip/hip_bf16.h>
#include <stdint.h>

typedef __attribute__((ext_vector_type(4))) int i32x4;
typedef __attribute__((ext_vector_type(16))) int i32x16;
typedef signed char s8;

#define M_TOT 8192
#define N_TOT 8192
#define K_TOT 2048
#define W_COUNT (N_TOT * K_TOT)
#define X_COUNT (M_TOT * K_TOT)

// ---------------- 1. fused deterministic reductions: sum|w| (double), max|x| ----------
__global__ void tl_reduce(const float* __restrict__ w, const float* __restrict__ x,
                          double* __restrict__ wsum, float* __restrict__ xmax) {
    const int b = blockIdx.x;
    if (b < 1024) {
        const int tid = b * 256 + threadIdx.x;
        const float4* w4 = (const float4*)w;
        double s = 0.0;
        for (int i = tid; i < W_COUNT / 4; i += 1024 * 256) {
            float4 v = w4[i];
            s += (double)fabsf(v.x) + (double)fabsf(v.y) + (double)fabsf(v.z) + (double)fabsf(v.w);
        }
        #pragma unroll
        for (int off = 32; off > 0; off >>= 1) s += __shfl_down(s, off);
        __shared__ double red[4];
        if ((threadIdx.x & 63) == 0) red[threadIdx.x >> 6] = s;
        __syncthreads();
        if (threadIdx.x == 0) wsum[b] = (red[0] + red[1]) + (red[2] + red[3]);
    } else {
        const int tid = (b - 1024) * 256 + threadIdx.x;
        const float4* x4 = (const float4*)x;
        float m = 0.0f;
        for (int i = tid; i < X_COUNT / 4; i += 1024 * 256) {
            float4 v = x4[i];
            m = fmaxf(m, fmaxf(fmaxf(fabsf(v.x), fabsf(v.y)), fmaxf(fabsf(v.z), fabsf(v.w))));
        }
        #pragma unroll
        for (int off = 32; off > 0; off >>= 1) m = fmaxf(m, __shfl_down(m, off));
        __shared__ float redm[4];
        if ((threadIdx.x & 63) == 0) redm[threadIdx.x >> 6] = m;
        __syncthreads();
        if (threadIdx.x == 0) xmax[b - 1024] = fmaxf(fmaxf(redm[0], redm[1]), fmaxf(redm[2], redm[3]));
    }
}

__global__ void tl_finalize(const double* __restrict__ wsum, const float* __restrict__ xmax,
                            const float* __restrict__ alpha,
                            double* __restrict__ delta, float* __restrict__ qp) {
    const int t = threadIdx.x;
    double s = (wsum[t] + wsum[t + 256]) + (wsum[t + 512] + wsum[t + 768]);
    float m = fmaxf(fmaxf(xmax[t], xmax[t + 256]), fmaxf(xmax[t + 512], xmax[t + 768]));
    #pragma unroll
    for (int off = 32; off > 0; off >>= 1) {
        s += __shfl_down(s, off);
        m = fmaxf(m, __shfl_down(m, off));
    }
    __shared__ double rs[4];
    __shared__ float rm[4];
    if ((t & 63) == 0) { rs[t >> 6] = s; rm[t >> 6] = m; }
    __syncthreads();
    if (t == 0) {
        *delta = 0.7 * (((rs[0] + rs[1]) + (rs[2] + rs[3])) / (double)W_COUNT);
        float mm = fmaxf(fmaxf(rm[0], rm[1]), fmaxf(rm[2], rm[3]));
        qp[0] = 127.0f / mm;                   // x quant scale
        qp[1] = alpha[0] * (mm / 127.0f);      // output scale
    }
}

// ---------------- 2. ternarize w -> i8 {-1,0,+1} ----------------
__global__ void tl_tern_w(const float* __restrict__ w, const double* __restrict__ delta_p,
                          s8* __restrict__ wb) {
    const double d = *delta_p;
    const int i = (blockIdx.x * 256 + threadIdx.x) * 16;
    union { s8 c[16]; i32x4 v; } o;
    #pragma unroll
    for (int j = 0; j < 16; j += 4) {
        float4 v = *(const float4*)(w + i + j);
        float f[4] = {v.x, v.y, v.z, v.w};
        #pragma unroll
        for (int r = 0; r < 4; ++r) {
            double wd = (double)f[r];
            o.c[j + r] = wd > d ? 1 : (wd < -d ? -1 : 0);
        }
    }
    *(i32x4*)(wb + i) = o.v;
}

// ---------------- 3. quantize x -> i8 (RNE, clamp 127) ----------------
__global__ void tl_quant_x(const float* __restrict__ x, const float* __restrict__ qp,
                           s8* __restrict__ xb) {
    const float inv = qp[0];
    const int i = (blockIdx.x * 256 + threadIdx.x) * 16;
    union { s8 c[16]; i32x4 v; } o;
    #pragma unroll
    for (int j = 0; j < 16; j += 4) {
        float4 v = *(const float4*)(x + i + j);
        float f[4] = {v.x, v.y, v.z, v.w};
        #pragma unroll
        for (int r = 0; r < 4; ++r) {
            int q = (int)__builtin_rintf(f[r] * inv);
            q = q > 127 ? 127 : (q < -127 ? -127 : q);
            o.c[j + r] = (s8)q;
        }
    }
    *(i32x4*)(xb + i) = o.v;
}

// ---------------- 4. i8 MFMA GEMM, 256x256 tile, BK=64, 32x32x32, 3-slot LDS -------
// C[m][n] = out_scale * (sum_k xq[m][k]*wt[n][k]) + bias[n]
// 512 threads = 8 waves (2 Mrows x 4 Ncols); wave owns 128x64 of C = 4x2 32x32 tiles.
// LDS: A slots s*16384, B slots 49152+s*16384, s=0..2 (96 KiB).
// Slot layout [256 rows][64 k] i8. Swizzle: col-slot ^= (row>>1)&3 (2-way = free).
// Per K-tile: 2 balanced phases {6 ds_read_b128 + 2 glds, bar, lgkm0, 8 MFMA, bar};
// stage tile t+2; gate vmcnt(4) once per K-tile.

#define SB    __builtin_amdgcn_sched_barrier(0)
#define BARR  __builtin_amdgcn_s_barrier()
#define LGKM0 asm volatile("s_waitcnt lgkmcnt(0)" ::: "memory")
#define VMW(N) asm volatile("s_waitcnt vmcnt(" #N ")" ::: "memory")

#define GLDS(SRC, DOFF) __builtin_amdgcn_global_load_lds(                      \
    (const __attribute__((address_space(1))) void*)(SRC),                      \
    (__attribute__((address_space(3))) void*)(lds + (DOFF)), 16, 0, 0)

#define RD_A(S, KK) do {                                                       \
    _Pragma("unroll") for (int m_ = 0; m_ < 4; ++m_)                           \
        aF[m_] = *(const i32x4*)(lds + (S) * 16384 + wrOff + m_ * 2048 +       \
                                 (lrd ^ ((KK) * 32)));                         \
} while (0)

#define RD_B(S, KK) do {                                                       \
    _Pragma("unroll") for (int n_ = 0; n_ < 2; ++n_)                           \
        bF[n_] = *(const i32x4*)(lds + 49152 + (S) * 16384 + wcOff + n_ * 2048 + \
                                 (lrd ^ ((KK) * 32)));                         \
} while (0)

#define MM() do {                                                              \
    _Pragma("unroll") for (int m_ = 0; m_ < 4; ++m_)                           \
    _Pragma("unroll") for (int n_ = 0; n_ < 2; ++n_)                           \
        acc[m_][n_] = __builtin_amdgcn_mfma_i32_32x32x32_i8(                   \
            aF[m_], bF[n_], acc[m_][n_], 0, 0, 0);                             \
} while (0)

#define KTILE(S, SSTG, KOFF, DOSTG, GATE) do {                                 \
    /* phase 0: k-half 0; stage A halves of tile t+2 */                        \
    RD_A(S, 0); RD_B(S, 0);                                                    \
    if (DOSTG) { GLDS(aSrc + (KOFF), (SSTG) * 16384 + L);                      \
                 GLDS(aSrc + (KOFF) + 262144, (SSTG) * 16384 + 8192 + L); }    \
    SB; BARR; LGKM0; SB;                                                       \
    __builtin_amdgcn_s_setprio(1); MM(); __builtin_amdgcn_s_setprio(0); SB; BARR; \
    /* phase 1: k-half 1; stage B halves */                                    \
    RD_A(S, 1); RD_B(S, 1);                                                    \
    if (DOSTG) { GLDS(bSrc + (KOFF), 49152 + (SSTG) * 16384 + L);              \
                 GLDS(bSrc + (KOFF) + 262144, 49152 + (SSTG) * 16384 + 8192 + L); } \
    SB; BARR; LGKM0; SB;                                                       \
    __builtin_amdgcn_s_setprio(1); MM(); __builtin_amdgcn_s_setprio(0); SB;    \
    GATE; BARR;                                                                \
} while (0)

__global__ __launch_bounds__(512, 1) void tl_gemm_i8(
    const s8* __restrict__ A, const s8* __restrict__ Bm,
    const float* __restrict__ qp, const float* __restrict__ bias,
    float* __restrict__ C) {
    __shared__ __attribute__((aligned(128))) char lds[98304];  // 96 KiB

    const int t = threadIdx.x;
    const int wid = t >> 6;
    const int l = t & 63;
    const int wr = wid >> 2;   // 0..1
    const int wc = wid & 3;    // 0..3

    // rect XCD ordering: resident 32 blocks/XCD = 4tm x 8tn rectangle
    const int bid = blockIdx.x;
    const int x = bid & 7;
    const int j = bid >> 3;                       // 0..127
    const int tm = x * 4 + ((j >> 3) & 3);
    const int tn = (j >> 5) * 8 + (j & 7);
    const int row0 = tm * 256, col0 = tn * 256;

    // staging coords: linear LDS dest byte L holds logical offset
    // off = L ^ (((L>>7)&3)<<4)  i.e. col-slot ^= (row>>1)&3 (involution)
    const int L = t * 16;
    const int off = L ^ (((L >> 7) & 3) << 4);
    const int sr = off >> 6;          // 0..127 (row within half)
    const int kb = off & 63;          // 16-aligned k-byte
    const s8* aSrc = A + (size_t)(row0 + sr) * K_TOT + kb;
    const s8* bSrc = Bm + (size_t)(col0 + sr) * K_TOT + kb;

    // ds_read lane constants (32x32 fragment: row = l&31, k-group = l>>5)
    const int rl = l & 31, kg = l >> 5;
    const int lrd = rl * 64 + ((kg ^ ((rl >> 1) & 3)) << 4);
    const int wrOff = wr * 8192;      // 128 rows * 64 B
    const int wcOff = wc * 4096;      // 64 rows * 64 B

    i32x16 acc[4][2] = {};
    i32x4 aF[4], bF[2];

    // prologue: stage tiles 0 (slot0) and 1 (slot1)
    GLDS(aSrc, L);                    GLDS(aSrc + 262144, 8192 + L);
    GLDS(bSrc, 49152 + L);            GLDS(bSrc + 262144, 49152 + 8192 + L);
    GLDS(aSrc + 64, 16384 + L);       GLDS(aSrc + 64 + 262144, 16384 + 8192 + L);
    GLDS(bSrc + 64, 49152 + 16384 + L);
    GLDS(bSrc + 64 + 262144, 49152 + 16384 + 8192 + L);
    VMW(4); BARR;

    int koff = 128;   // staging byte offset for tile t+2
    #pragma unroll 1
    for (int i = 0; i < 10; ++i) {
        KTILE(0, 2, koff, 1, VMW(4)); koff += 64;
        KTILE(1, 0, koff, 1, VMW(4)); koff += 64;
        KTILE(2, 1, koff, 1, VMW(4)); koff += 64;
    }
    KTILE(0, 0, 0, 0, VMW(0));   // tile 30
    KTILE(1, 0, 0, 0, (void)0);  // tile 31

    // epilogue: C = out_scale * acc + bias
    // 32x32 C/D layout: col = l&31, row = (reg&3) + 8*(reg>>2) + 4*(l>>5)
    const float osc = qp[1];
    #pragma unroll
    for (int m_ = 0; m_ < 4; ++m_) {
        const int crow = row0 + wr * 128 + m_ * 32 + kg * 4;
        #pragma unroll
        for (int n_ = 0; n_ < 2; ++n_) {
            const int ccol = col0 + wc * 64 + n_ * 32 + rl;
            const float bv = bias[ccol];
            #pragma unroll
            for (int r = 0; r < 16; ++r) {
                const int row = crow + (r & 3) + 8 * (r >> 2);
                C[(size_t)row * N_TOT + ccol] = (float)acc[m_][n_][r] * osc + bv;
            }
        }
    }
}

extern "C" void kernel_launch(void* const* d_in, const int* in_sizes, int n_in,
                              void* d_out, int out_size, void* d_ws, size_t ws_size,
                              hipStream_t stream) {
    const float* x     = (const float*)d_in[0];
    const float* wgt   = (const float*)d_in[1];
    const float* alpha = (const float*)d_in[2];
    const float* bias  = (const float*)d_in[3];
    float* out = (float*)d_out;

    char* ws = (char*)d_ws;
    double* wsum = (double*)ws;               // 8 KB
    float* xmax  = (float*)(ws + 8192);       // 4 KB
    double* delta = (double*)(ws + 12288);
    float* qp     = (float*)(ws + 12304);     // [0]=127/max, [1]=alpha*max/127
    s8* xb = (s8*)(ws + 16384);               // 16 MB
    s8* wb = (s8*)(ws + 16384 + (size_t)X_COUNT);  // 16 MB

    tl_reduce<<<2048, 256, 0, stream>>>(wgt, x, wsum, xmax);
    tl_finalize<<<1, 256, 0, stream>>>(wsum, xmax, alpha, delta, qp);
    tl_tern_w<<<W_COUNT / (256 * 16), 256, 0, stream>>>(wgt, delta, wb);
    tl_quant_x<<<X_COUNT / (256 * 16), 256, 0, stream>>>(x, qp, xb);
    tl_gemm_i8<<<(M_TOT / 256) * (N_TOT / 256), 512, 0, stream>>>(xb, wb, qp, bias, out);
}